// Round 6
// baseline (347.035 us; speedup 1.0000x reference)
//
#include <hip/hip_runtime.h>

#define HEADS 16
#define HD 64
#define ROT 32
#define SEQ 4096
#define BROWS 256

typedef float sv16 __attribute__((ext_vector_type(16)));

// ---------------------------------------------------------------------------
// Setup: Wp[k][n] = sum_j M[k][j] * R[j][perm(n)], perm(n)=2n / 2(n-32)+1.
// Params (i,j,cos,sin) precomputed in parallel by 32 threads -> LDS, so the
// serial 32-step rotation has no global loads / transcendentals inside.
// ---------------------------------------------------------------------------
__global__ __launch_bounds__(256) void build_W_kernel(
    const float* __restrict__ thetas,
    const float* __restrict__ theta_scale,
    const float* __restrict__ r_matrix,
    const int* __restrict__ pairs,
    float* __restrict__ Wp)
{
    __shared__ float M[64][65];
    __shared__ float Rl[64][65];
    __shared__ int   ip[32], jp[32];
    __shared__ float cs[32], sn[32];
    const int tid = threadIdx.x;

    if (tid < 32) {
        const int i = pairs[2 * tid + 0];
        const int j = pairs[2 * tid + 1];
        float s, c;
        sincosf(thetas[tid] * theta_scale[0], &s, &c);
        ip[tid] = i; jp[tid] = j; cs[tid] = c; sn[tid] = s;
    }
    // stage r_matrix (4096 floats) coalesced
    #pragma unroll
    for (int it = 0; it < 16; ++it) {
        const int f = it * 256 + tid;
        Rl[f >> 6][f & 63] = r_matrix[f];
    }
    if (tid < 64) {
        #pragma unroll
        for (int k = 0; k < 64; ++k) M[tid][k] = (k == tid) ? 1.0f : 0.0f;
    }
    __syncthreads();

    if (tid < 64) {
        const int t = tid;
        #pragma unroll 1
        for (int r = 0; r < ROT; ++r) {
            const int i = ip[r];
            const int j = jp[r];
            const float c = cs[r];
            const float s = sn[r];
            const float xi = M[t][i];
            const float xj = M[t][j];
            const float gi =  xi * c + xj * s;
            const float gj = -xi * s + xj * c;
            const float ni = (2.0f * gi + xi - 2.0f * gi * c) / 3.0f;
            const float nj = (2.0f * gj + xj - 2.0f * gi * s) / 3.0f;
            M[t][i] = ni;
            M[t][j] = nj;
        }
    }
    __syncthreads();

    // Wp[k][n]: thread (kq = tid>>6, n = tid&63) computes 16 k's for its n.
    const int n = tid & 63;
    const int kq = tid >> 6;
    const int cn = (n < 32) ? (2 * n) : (2 * (n - 32) + 1);
    #pragma unroll 1
    for (int kk = 0; kk < 16; ++kk) {
        const int k = kq * 16 + kk;
        float acc = 0.0f;
        #pragma unroll
        for (int j = 0; j < 64; ++j) acc = fmaf(M[k][j], Rl[j][cn], acc);
        Wp[k * 64 + n] = acc;
    }
}

// ---------------------------------------------------------------------------
// Main fused kernel: out_row = RoPE_s( x_row @ Wp ).
// One thread = one 64-elem row. No LDS staging (per-thread float4 loads and
// stores cover full cache lines within the block); LDS = trig tables only.
// W rows stream through the SCALAR pipe, software-pipelined at half-row
// granularity: issue next 2x s_load_dwordx16, FMA current 32, then a
// data-carrying s_waitcnt lgkmcnt(0) ("+s" ties the loaded regs -> SSA dep,
// so FMAs can't hoist past the wait; SMEM is OoO so only lgkmcnt(0) is safe).
// All acc[]/xkf[] indices are compile-time constants (rule #20).
// ---------------------------------------------------------------------------
#define PREF(C0, C1, OA, OB) asm volatile(                       \
    "s_load_dwordx16 %0, %2, " #OA "\n\t"                         \
    "s_load_dwordx16 %1, %2, " #OB                                \
    : "=&s"(C0), "=&s"(C1) : "s"(wq))

#define WAITW(C0, C1) asm volatile("s_waitcnt lgkmcnt(0)" : "+s"(C0), "+s"(C1))

#define FMA32(C0, C1, M, H) do { const float xm_ = xkf[M];        \
    _Pragma("unroll")                                             \
    for (int i_ = 0; i_ < 16; ++i_) {                             \
        acc[(H)*32 + i_]      = fmaf(xm_, (C0)[i_], acc[(H)*32 + i_]);      \
        acc[(H)*32 + 16 + i_] = fmaf(xm_, (C1)[i_], acc[(H)*32 + 16 + i_]); \
    } } while (0)

__global__ __launch_bounds__(256, 5) void fused_main(
    const float* __restrict__ x,
    const float* __restrict__ Wp,
    const float* __restrict__ inv_freq,
    float* __restrict__ out)
{
    __shared__ float tc[16 * 33];        // cos table
    __shared__ float tsn[16 * 33];       // sin table

    const int tid = threadIdx.x;
    const int blk = blockIdx.x;
    const long long row = (long long)blk * BROWS + tid;
    const float4* __restrict__ xp4 = (const float4*)(x + row * HD);
    float4* __restrict__ op4 = (float4*)(out + row * HD);

    // trig table for this block's 16 sequence positions
    {
        const int s0 = (blk & (SEQ / 16 - 1)) * 16;
        #pragma unroll
        for (int u = 0; u < 2; ++u) {
            const int e = tid * 2 + u;
            const int sl = e >> 5;
            const int f = e & 31;
            const float ang = (float)(s0 + sl) * inv_freq[f];
            float s_, c_;
            sincosf(ang, &s_, &c_);
            tc[sl * 33 + f] = c_;
            tsn[sl * 33 + f] = s_;
        }
    }
    __syncthreads();   // the only barrier: tables read after the K-loop

    float acc[64];
    #pragma unroll
    for (int nn = 0; nn < 64; ++nn) acc[nn] = 0.0f;

    #pragma unroll 1
    for (int q = 0; q < 4; ++q) {
        // this quarter's 16 x-values (own row, cols [16q,16q+16)) — issued
        // up front so HBM latency hides under the W prologue + first FMAs
        float xkf[16];
        {
            const float4 t0 = xp4[q * 4 + 0];
            const float4 t1 = xp4[q * 4 + 1];
            const float4 t2 = xp4[q * 4 + 2];
            const float4 t3 = xp4[q * 4 + 3];
            xkf[0]=t0.x;  xkf[1]=t0.y;  xkf[2]=t0.z;  xkf[3]=t0.w;
            xkf[4]=t1.x;  xkf[5]=t1.y;  xkf[6]=t1.z;  xkf[7]=t1.w;
            xkf[8]=t2.x;  xkf[9]=t2.y;  xkf[10]=t2.z; xkf[11]=t2.w;
            xkf[12]=t3.x; xkf[13]=t3.y; xkf[14]=t3.z; xkf[15]=t3.w;
        }
        const float* wq = Wp + q * 1024;   // rows [16q,16q+16) of W (uniform)
        sv16 A0, A1, B0, B1;

        PREF(A0, A1, 0, 64);            WAITW(A0, A1);
        PREF(B0, B1, 128, 192);   FMA32(A0, A1, 0, 0);  WAITW(B0, B1);
        PREF(A0, A1, 256, 320);   FMA32(B0, B1, 0, 1);  WAITW(A0, A1);
        PREF(B0, B1, 384, 448);   FMA32(A0, A1, 1, 0);  WAITW(B0, B1);
        PREF(A0, A1, 512, 576);   FMA32(B0, B1, 1, 1);  WAITW(A0, A1);
        PREF(B0, B1, 640, 704);   FMA32(A0, A1, 2, 0);  WAITW(B0, B1);
        PREF(A0, A1, 768, 832);   FMA32(B0, B1, 2, 1);  WAITW(A0, A1);
        PREF(B0, B1, 896, 960);   FMA32(A0, A1, 3, 0);  WAITW(B0, B1);
        PREF(A0, A1, 1024, 1088); FMA32(B0, B1, 3, 1);  WAITW(A0, A1);
        PREF(B0, B1, 1152, 1216); FMA32(A0, A1, 4, 0);  WAITW(B0, B1);
        PREF(A0, A1, 1280, 1344); FMA32(B0, B1, 4, 1);  WAITW(A0, A1);
        PREF(B0, B1, 1408, 1472); FMA32(A0, A1, 5, 0);  WAITW(B0, B1);
        PREF(A0, A1, 1536, 1600); FMA32(B0, B1, 5, 1);  WAITW(A0, A1);
        PREF(B0, B1, 1664, 1728); FMA32(A0, A1, 6, 0);  WAITW(B0, B1);
        PREF(A0, A1, 1792, 1856); FMA32(B0, B1, 6, 1);  WAITW(A0, A1);
        PREF(B0, B1, 1920, 1984); FMA32(A0, A1, 7, 0);  WAITW(B0, B1);
        PREF(A0, A1, 2048, 2112); FMA32(B0, B1, 7, 1);  WAITW(A0, A1);
        PREF(B0, B1, 2176, 2240); FMA32(A0, A1, 8, 0);  WAITW(B0, B1);
        PREF(A0, A1, 2304, 2368); FMA32(B0, B1, 8, 1);  WAITW(A0, A1);
        PREF(B0, B1, 2432, 2496); FMA32(A0, A1, 9, 0);  WAITW(B0, B1);
        PREF(A0, A1, 2560, 2624); FMA32(B0, B1, 9, 1);  WAITW(A0, A1);
        PREF(B0, B1, 2688, 2752); FMA32(A0, A1, 10, 0); WAITW(B0, B1);
        PREF(A0, A1, 2816, 2880); FMA32(B0, B1, 10, 1); WAITW(A0, A1);
        PREF(B0, B1, 2944, 3008); FMA32(A0, A1, 11, 0); WAITW(B0, B1);
        PREF(A0, A1, 3072, 3136); FMA32(B0, B1, 11, 1); WAITW(A0, A1);
        PREF(B0, B1, 3200, 3264); FMA32(A0, A1, 12, 0); WAITW(B0, B1);
        PREF(A0, A1, 3328, 3392); FMA32(B0, B1, 12, 1); WAITW(A0, A1);
        PREF(B0, B1, 3456, 3520); FMA32(A0, A1, 13, 0); WAITW(B0, B1);
        PREF(A0, A1, 3584, 3648); FMA32(B0, B1, 13, 1); WAITW(A0, A1);
        PREF(B0, B1, 3712, 3776); FMA32(A0, A1, 14, 0); WAITW(B0, B1);
        PREF(A0, A1, 3840, 3904); FMA32(B0, B1, 14, 1); WAITW(A0, A1);
        PREF(B0, B1, 3968, 4032); FMA32(A0, A1, 15, 0); WAITW(B0, B1);
        FMA32(B0, B1, 15, 1);
    }

    // RoPE combine: out col n (n<32) from acc[n], acc[32+n] (concat halves)
    {
        const int sl = tid >> 4;
        #pragma unroll
        for (int n = 0; n < 32; ++n) {
            const float c = tc[sl * 33 + n];
            const float s = tsn[sl * 33 + n];
            const float a = acc[n];
            const float b = acc[32 + n];
            acc[n]      = a * c - b * s;
            acc[32 + n] = a * s + b * c;
        }
    }

    // direct store: own row, 16x float4 (every 128B line fully written)
    #pragma unroll
    for (int c = 0; c < 16; ++c) {
        op4[c] = make_float4(acc[4 * c + 0], acc[4 * c + 1],
                             acc[4 * c + 2], acc[4 * c + 3]);
    }
}

extern "C" void kernel_launch(void* const* d_in, const int* in_sizes, int n_in,
                              void* d_out, int out_size, void* d_ws, size_t ws_size,
                              hipStream_t stream) {
    const float* x   = (const float*)d_in[0];
    const float* th  = (const float*)d_in[1];
    const float* sc  = (const float*)d_in[2];
    const float* R   = (const float*)d_in[3];
    const float* ivf = (const float*)d_in[4];
    const int*   pr  = (const int*)d_in[5];
    float* W = (float*)d_ws;   // 64*64 floats = 16 KB scratch

    build_W_kernel<<<1, 256, 0, stream>>>(th, sc, R, pr, W);

    const int rows = out_size / HD;        // 524,288
    const int blocks = rows / BROWS;       // 2,048
    fused_main<<<blocks, 256, 0, stream>>>(x, W, ivf, (float*)d_out);
}

// Round 7
// 290.691 us; speedup vs baseline: 1.1938x; 1.1938x over previous
//
#include <hip/hip_runtime.h>

#define HEADS 16
#define HD 64
#define ROT 32
#define SEQ 4096
#define BROWS 256
#define PADW 33   // half-row stride in floats (32 data + 1 pad)

typedef float sv16 __attribute__((ext_vector_type(16)));

// ---------------------------------------------------------------------------
// Setup: Wp[k][n] = sum_j M[k][j] * R[j][perm(n)], perm(n)=2n / 2(n-32)+1.
// Params (i,j,cos,sin) precomputed in parallel by 32 threads -> LDS, so the
// serial 32-step rotation has no global loads / transcendentals inside.
// ---------------------------------------------------------------------------
__global__ __launch_bounds__(256) void build_W_kernel(
    const float* __restrict__ thetas,
    const float* __restrict__ theta_scale,
    const float* __restrict__ r_matrix,
    const int* __restrict__ pairs,
    float* __restrict__ Wp)
{
    __shared__ float M[64][65];
    __shared__ float Rl[64][65];
    __shared__ int   ip[32], jp[32];
    __shared__ float cs[32], sn[32];
    const int tid = threadIdx.x;

    if (tid < 32) {
        const int i = pairs[2 * tid + 0];
        const int j = pairs[2 * tid + 1];
        float s, c;
        sincosf(thetas[tid] * theta_scale[0], &s, &c);
        ip[tid] = i; jp[tid] = j; cs[tid] = c; sn[tid] = s;
    }
    #pragma unroll
    for (int it = 0; it < 16; ++it) {
        const int f = it * 256 + tid;
        Rl[f >> 6][f & 63] = r_matrix[f];
    }
    if (tid < 64) {
        #pragma unroll
        for (int k = 0; k < 64; ++k) M[tid][k] = (k == tid) ? 1.0f : 0.0f;
    }
    __syncthreads();

    if (tid < 64) {
        const int t = tid;
        #pragma unroll 1
        for (int r = 0; r < ROT; ++r) {
            const int i = ip[r];
            const int j = jp[r];
            const float c = cs[r];
            const float s = sn[r];
            const float xi = M[t][i];
            const float xj = M[t][j];
            const float gi =  xi * c + xj * s;
            const float gj = -xi * s + xj * c;
            const float ni = (2.0f * gi + xi - 2.0f * gi * c) / 3.0f;
            const float nj = (2.0f * gj + xj - 2.0f * gi * s) / 3.0f;
            M[t][i] = ni;
            M[t][j] = nj;
        }
    }
    __syncthreads();

    const int n = tid & 63;
    const int kq = tid >> 6;
    const int cn = (n < 32) ? (2 * n) : (2 * (n - 32) + 1);
    #pragma unroll 1
    for (int kk = 0; kk < 16; ++kk) {
        const int k = kq * 16 + kk;
        float acc = 0.0f;
        #pragma unroll
        for (int j = 0; j < 64; ++j) acc = fmaf(M[k][j], Rl[j][cn], acc);
        Wp[k * 64 + n] = acc;
    }
}

// ---------------------------------------------------------------------------
// Pipelined scalar-pipe W ladder: 16 W-rows (4 KB) per call. Per step: issue
// next half-row (2x s_load_dwordx16), FMA current 32 floats, then a
// data-carrying s_waitcnt lgkmcnt(0) ("+s" ties loaded regs -> SSA dep, so
// FMAs can't hoist past the wait; SMEM completes OoO so only lgkmcnt(0) is
// safe). All acc/xkf indices compile-time (rule #20).
// ---------------------------------------------------------------------------
#define PREF(C0, C1, OA, OB) asm volatile(                        \
    "s_load_dwordx16 %0, %2, " #OA "\n\t"                         \
    "s_load_dwordx16 %1, %2, " #OB                                \
    : "=&s"(C0), "=&s"(C1) : "s"(wq))

#define WAITW(C0, C1) asm volatile("s_waitcnt lgkmcnt(0)" : "+s"(C0), "+s"(C1))

#define FMA32(C0, C1, M, H) do { const float xm_ = xkf[M];                  \
    _Pragma("unroll")                                                       \
    for (int i_ = 0; i_ < 16; ++i_) {                                       \
        acc[(H)*32 + i_]      = fmaf(xm_, (C0)[i_], acc[(H)*32 + i_]);      \
        acc[(H)*32 + 16 + i_] = fmaf(xm_, (C1)[i_], acc[(H)*32 + 16 + i_]); \
    } } while (0)

__device__ __forceinline__ void quarter_ladder(const float* __restrict__ wq,
                                               const float (&xkf)[16],
                                               float (&acc)[64])
{
    sv16 A0, A1, B0, B1;
    PREF(A0, A1, 0, 64);            WAITW(A0, A1);
    PREF(B0, B1, 128, 192);   FMA32(A0, A1, 0, 0);  WAITW(B0, B1);
    PREF(A0, A1, 256, 320);   FMA32(B0, B1, 0, 1);  WAITW(A0, A1);
    PREF(B0, B1, 384, 448);   FMA32(A0, A1, 1, 0);  WAITW(B0, B1);
    PREF(A0, A1, 512, 576);   FMA32(B0, B1, 1, 1);  WAITW(A0, A1);
    PREF(B0, B1, 640, 704);   FMA32(A0, A1, 2, 0);  WAITW(B0, B1);
    PREF(A0, A1, 768, 832);   FMA32(B0, B1, 2, 1);  WAITW(A0, A1);
    PREF(B0, B1, 896, 960);   FMA32(A0, A1, 3, 0);  WAITW(B0, B1);
    PREF(A0, A1, 1024, 1088); FMA32(B0, B1, 3, 1);  WAITW(A0, A1);
    PREF(B0, B1, 1152, 1216); FMA32(A0, A1, 4, 0);  WAITW(B0, B1);
    PREF(A0, A1, 1280, 1344); FMA32(B0, B1, 4, 1);  WAITW(A0, A1);
    PREF(B0, B1, 1408, 1472); FMA32(A0, A1, 5, 0);  WAITW(B0, B1);
    PREF(A0, A1, 1536, 1600); FMA32(B0, B1, 5, 1);  WAITW(A0, A1);
    PREF(B0, B1, 1664, 1728); FMA32(A0, A1, 6, 0);  WAITW(B0, B1);
    PREF(A0, A1, 1792, 1856); FMA32(B0, B1, 6, 1);  WAITW(A0, A1);
    PREF(B0, B1, 1920, 1984); FMA32(A0, A1, 7, 0);  WAITW(B0, B1);
    PREF(A0, A1, 2048, 2112); FMA32(B0, B1, 7, 1);  WAITW(A0, A1);
    PREF(B0, B1, 2176, 2240); FMA32(A0, A1, 8, 0);  WAITW(B0, B1);
    PREF(A0, A1, 2304, 2368); FMA32(B0, B1, 8, 1);  WAITW(A0, A1);
    PREF(B0, B1, 2432, 2496); FMA32(A0, A1, 9, 0);  WAITW(B0, B1);
    PREF(A0, A1, 2560, 2624); FMA32(B0, B1, 9, 1);  WAITW(A0, A1);
    PREF(B0, B1, 2688, 2752); FMA32(A0, A1, 10, 0); WAITW(B0, B1);
    PREF(A0, A1, 2816, 2880); FMA32(B0, B1, 10, 1); WAITW(A0, A1);
    PREF(B0, B1, 2944, 3008); FMA32(A0, A1, 11, 0); WAITW(B0, B1);
    PREF(A0, A1, 3072, 3136); FMA32(B0, B1, 11, 1); WAITW(A0, A1);
    PREF(B0, B1, 3200, 3264); FMA32(A0, A1, 12, 0); WAITW(B0, B1);
    PREF(A0, A1, 3328, 3392); FMA32(B0, B1, 12, 1); WAITW(A0, A1);
    PREF(B0, B1, 3456, 3520); FMA32(A0, A1, 13, 0); WAITW(B0, B1);
    PREF(A0, A1, 3584, 3648); FMA32(B0, B1, 13, 1); WAITW(A0, A1);
    PREF(B0, B1, 3712, 3776); FMA32(A0, A1, 14, 0); WAITW(B0, B1);
    PREF(A0, A1, 3840, 3904); FMA32(B0, B1, 14, 1); WAITW(A0, A1);
    PREF(B0, B1, 3968, 4032); FMA32(A0, A1, 15, 0); WAITW(B0, B1);
    FMA32(B0, B1, 15, 1);
}

// ---------------------------------------------------------------------------
// Main fused kernel: out_row = RoPE_s( x_row @ Wp ).
// R5 skeleton (proven clean traffic, spill-free): x staged via LDS
// (coalesced float4, pad-33 conflict-free), write-back via LDS; plus the
// pipelined scalar ladder for W. launch_bounds(256,4) -> 128-VGPR cap.
// ---------------------------------------------------------------------------
__global__ __launch_bounds__(256, 4) void fused_main(
    const float* __restrict__ x,
    const float* __restrict__ Wp,
    const float* __restrict__ inv_freq,
    float* __restrict__ out)
{
    __shared__ float xs[BROWS * PADW];   // 33,792 B
    __shared__ float tc[16 * 33];        // cos table
    __shared__ float tsn[16 * 33];       // sin table

    const int tid = threadIdx.x;
    const int blk = blockIdx.x;
    const long long base4 = (long long)blk * (BROWS * HD / 4);
    const float4* __restrict__ xv = (const float4*)x + base4;
    float4* __restrict__ ov = (float4*)out + base4;

    // trig table for this block's 16 sequence positions
    {
        const int s0 = (blk & (SEQ / 16 - 1)) * 16;
        #pragma unroll
        for (int u = 0; u < 2; ++u) {
            const int e = tid * 2 + u;
            const int sl = e >> 5;
            const int f = e & 31;
            const float ang = (float)(s0 + sl) * inv_freq[f];
            float s_, c_;
            sincosf(ang, &s_, &c_);
            tc[sl * 33 + f] = c_;
            tsn[sl * 33 + f] = s_;
        }
    }

    float acc[64];
    #pragma unroll
    for (int nn = 0; nn < 64; ++nn) acc[nn] = 0.0f;

    #pragma unroll 1
    for (int half = 0; half < 2; ++half) {
        __syncthreads();   // half 0: trig visible; half 1: prior xs readers done
        #pragma unroll
        for (int it = 0; it < 8; ++it) {
            const int f = it * 256 + tid;
            const int row = f >> 3;
            const int c4 = f & 7;
            const float4 v = xv[row * 16 + half * 8 + c4];
            float* p = &xs[row * PADW + c4 * 4];
            p[0] = v.x; p[1] = v.y; p[2] = v.z; p[3] = v.w;
        }
        __syncthreads();

        const float* xrow = &xs[tid * PADW];
        #pragma unroll 1
        for (int kc = 0; kc < 2; ++kc) {
            float xkf[16];
            #pragma unroll
            for (int m = 0; m < 16; ++m) xkf[m] = xrow[kc * 16 + m];
            quarter_ladder(Wp + (half * 32 + kc * 16) * 64, xkf, acc);
        }
    }

    // RoPE combine: acc[0..31] = even cols, acc[32..63] = odd cols
    {
        const int sl = tid >> 4;
        #pragma unroll
        for (int n = 0; n < 32; ++n) {
            const float c = tc[sl * 33 + n];
            const float s = tsn[sl * 33 + n];
            const float a = acc[n];
            const float b = acc[32 + n];
            acc[n]      = a * c - b * s;
            acc[32 + n] = a * s + b * c;
        }
    }

    // write back through LDS for coalesced stores — TWO EXPLICIT halves so
    // every acc[] index is a compile-time constant (no scratch allocation).
    {
        float* prow = &xs[tid * PADW];
        // ---- half 0: out cols 0..31 = acc[0..31] ----
        __syncthreads();
        #pragma unroll
        for (int n = 0; n < 32; ++n) prow[n] = acc[n];
        __syncthreads();
        #pragma unroll
        for (int it = 0; it < 8; ++it) {
            const int f = it * 256 + tid;
            const int row = f >> 3;
            const int c4 = f & 7;
            const float* p = &xs[row * PADW + c4 * 4];
            ov[row * 16 + c4] = make_float4(p[0], p[1], p[2], p[3]);
        }
        // ---- half 1: out cols 32..63 = acc[32..63] ----
        __syncthreads();
        #pragma unroll
        for (int n = 0; n < 32; ++n) prow[n] = acc[32 + n];
        __syncthreads();
        #pragma unroll
        for (int it = 0; it < 8; ++it) {
            const int f = it * 256 + tid;
            const int row = f >> 3;
            const int c4 = f & 7;
            const float* p = &xs[row * PADW + c4 * 4];
            ov[row * 16 + 8 + c4] = make_float4(p[0], p[1], p[2], p[3]);
        }
    }
}

extern "C" void kernel_launch(void* const* d_in, const int* in_sizes, int n_in,
                              void* d_out, int out_size, void* d_ws, size_t ws_size,
                              hipStream_t stream) {
    const float* x   = (const float*)d_in[0];
    const float* th  = (const float*)d_in[1];
    const float* sc  = (const float*)d_in[2];
    const float* R   = (const float*)d_in[3];
    const float* ivf = (const float*)d_in[4];
    const int*   pr  = (const int*)d_in[5];
    float* W = (float*)d_ws;   // 64*64 floats = 16 KB scratch

    build_W_kernel<<<1, 256, 0, stream>>>(th, sc, R, pr, W);

    const int rows = out_size / HD;        // 524,288
    const int blocks = rows / BROWS;       // 2,048
    fused_main<<<blocks, 256, 0, stream>>>(x, W, ivf, (float*)d_out);
}